// Round 12
// baseline (90.639 us; speedup 1.0000x reference)
//
#include <hip/hip_runtime.h>
#include <stdint.h>

typedef int i32x4 __attribute__((ext_vector_type(4)));
typedef int i32x8 __attribute__((ext_vector_type(8)));
typedef float f32x4 __attribute__((ext_vector_type(4)));

#define B_ROWS 4096
#define C_COLS 32768
#define D_DIM 256
// log2(e) / 0.05
#define LOG2E_OVER_TEMP 28.853900817779268f

#define BM 256                  // rows per block (8 waves x 32 rows)
#define BC 64                   // cols per LDS tile (16 KB/tile, dbuf = 32 KB)
#define CSPLIT 64
#define CPB (C_COLS / CSPLIT)   // 512 cols per block
#define CTILES (CPB / BC)       // 8 tiles
#define NWAVES 8
#define TILE_BYTES (BC * D_DIM) // 16384 (fp8)
#define CVT_TILES (C_COLS / BC) // 512

typedef __attribute__((address_space(3))) char lds_char_t;
typedef __attribute__((address_space(1))) const char glb_char_t;

// pack 4 f32 -> 4 fp8 e4m3 bytes in one dword (saturating HW cvt)
__device__ __forceinline__ int pack4_fp8(float a, float b, float c, float d) {
  int r = 0;
  r = __builtin_amdgcn_cvt_pk_fp8_f32(a, b, r, false);  // bytes 0,1
  r = __builtin_amdgcn_cvt_pk_fp8_f32(c, d, r, true);   // bytes 2,3
  return r;
}

// ---- kernel 1: prep ----
// blocks [0, 512):  centrals f32 -> fp8 e4m3, permuted per-tile:
//   cq[tile][kb(8)][half(2)][col(64)][16B], 16 KB/tile. Reads fully coalesced
//   (lane i reads 64B at tsrc + 64*i, linear sweep); 16B permuted writes merge
//   into 64B wave segments. (r10 lesson: coalesce the fp32 read side, it is
//   4x the write bytes.)
// blocks [512, ...): row-normalize x (pre-scaled by log2e/T) -> fp8 xq,
//   plus exact fp32 label logit -> elab. One wave per row.
__global__ void prep_all(const float* __restrict__ x, const float* __restrict__ cent,
                         const int* __restrict__ labels, uint8_t* __restrict__ cq,
                         uint8_t* __restrict__ xq, float* __restrict__ elab) {
  int blk = blockIdx.x;
  if (blk < CVT_TILES) {
    int ct = blk;
    const float* tsrc = cent + (size_t)ct * BC * D_DIM;
    uint8_t* tdst = cq + (size_t)ct * TILE_BYTES;
    #pragma unroll
    for (int i = 0; i < 4; i++) {
      int c = i * 256 + threadIdx.x;      // chunk 0..1023: 16 consecutive floats
      int col = c >> 4;                   // 0..63 (central row within tile)
      int k16 = c & 15;                   // 16-float k group
      const float* src = tsrc + c * 16;   // coalesced
      int4 o;
      float4 v;
      v = ((const float4*)src)[0]; o.x = pack4_fp8(v.x, v.y, v.z, v.w);
      v = ((const float4*)src)[1]; o.y = pack4_fp8(v.x, v.y, v.z, v.w);
      v = ((const float4*)src)[2]; o.z = pack4_fp8(v.x, v.y, v.z, v.w);
      v = ((const float4*)src)[3]; o.w = pack4_fp8(v.x, v.y, v.z, v.w);
      // permuted slot: kb = k16>>1, half = k16&1
      int off = (k16 >> 1) * 2048 + (k16 & 1) * 1024 + col * 16;
      *(int4*)(tdst + off) = o;
    }
  } else {
    int row = (blk - CVT_TILES) * (blockDim.x >> 6) + (threadIdx.x >> 6);
    int lane = threadIdx.x & 63;
    int lab = labels[row];
    const float4 xv = *(const float4*)(x + (size_t)row * D_DIM + lane * 4);
    const float4 cv = *(const float4*)(cent + (size_t)lab * D_DIM + lane * 4);
    float ss = xv.x * xv.x + xv.y * xv.y + xv.z * xv.z + xv.w * xv.w;
    float dc = xv.x * cv.x + xv.y * cv.y + xv.z * cv.z + xv.w * cv.w;
    #pragma unroll
    for (int m = 1; m < 64; m <<= 1) {
      ss += __shfl_xor(ss, m, 64);
      dc += __shfl_xor(dc, m, 64);
    }
    float inv = 1.0f / sqrtf(ss);
    float sc = inv * LOG2E_OVER_TEMP;   // pre-scale: GEMM acc is the exp2 arg
    *(int*)(xq + (size_t)row * D_DIM + lane * 4) =
        pack4_fp8(xv.x * sc, xv.y * sc, xv.z * sc, xv.w * sc);
    if (lane == 0) elab[row] = exp2f(dc * inv * LOG2E_OVER_TEMP);
  }
}

// ---- staging: async global->LDS, 16B/lane, fully linear (cq pre-permuted) ----
// 8 waves: each wave issues 2 chunk-rows of the 16 KB tile.
__device__ __forceinline__ void stage_tile(const uint8_t* __restrict__ src, char* buf,
                                           int w, int lane) {
  #pragma unroll
  for (int i = 0; i < 2; i++) {
    int slot_hi = i * NWAVES + w;          // wave-uniform, 0..15
    __builtin_amdgcn_global_load_lds(
        (glb_char_t*)(const void*)(src + slot_hi * 1024 + lane * 16),
        (lds_char_t*)(void*)(buf + slot_hi * 1024), 16, 0, 0);
  }
}

// ---- kernel 2: fused MX-fp8 GEMM + exp + row-sum ----
// 1024 blocks x 512 threads (8 waves x 32 rows).  TLP fix (rounds 2-11): at
// 64 rows/wave (4 waves) the block runs 2 waves/SIMD and every __syncthreads
// idles the SIMD; 32 rows/wave drops A to 32 regs (demand ~110 < 128 cap) so
// __launch_bounds__(512,4) gives 2 blocks/CU = 4 waves/SIMD -- double TLP,
// bit-identical per-row arithmetic.
// B tile 64 cols x 256 k fp8 = 16 KB dbuf, K-block-major:
//   chunk (col, kb, half) at byte kb*2048 + half*1024 + col*16.
// MFMA: mfma_scale_f32_16x16x128_f8f6f4, unit scales (e8m0 0x7F = 2^0).
// SPILL GUARDS: B-frag = two i32x4 LDS reads (never one i32x8 deref); watch
// for the VGPR_Count=84 + WRITE_SIZE>>MB signature.
__global__ void __launch_bounds__(512, 4)
gemm_expsum(const uint8_t* __restrict__ xq, const uint8_t* __restrict__ cq,
            float* __restrict__ partials) {
  __shared__ char Bs[2][TILE_BYTES];   // 2 x 16 KB
  const int tid = threadIdx.x;
  const int w = tid >> 6, lane = tid & 63;
  const int fr = lane & 15, kq = lane >> 4;

  // XCD-aware decode: xcd = bid&7 owns cs in [xcd*8, xcd*8+8); within an xcd,
  // consecutive j sweep row-blocks of the SAME cs -> B slice stays L2-hot.
  const int bid = blockIdx.x;
  const int xcd = bid & 7;
  const int j = bid >> 3;                  // 0..127
  const int bx = j & 15;                   // row-block 0..15
  const int cs = xcd * 8 + (j >> 4);       // col-split 0..63
  const int brow0 = bx * BM;
  const int tile0 = cs * CTILES;           // global 64-col tile index

  // A fragments: rows brow0 + w*32 + rf*16 + fr; k = kh*128 + kq*32 .. +32
  i32x8 a[2][2];
  #pragma unroll
  for (int rf = 0; rf < 2; rf++) {
    int row = brow0 + w * 32 + rf * 16 + fr;
    #pragma unroll
    for (int kh = 0; kh < 2; kh++)
      a[rf][kh] = *(const i32x8*)(xq + (size_t)row * D_DIM + kh * 128 + kq * 32);
  }

  float s[2][4] = {{0.f,0.f,0.f,0.f},{0.f,0.f,0.f,0.f}};
  const f32x4 vzero = {0.f, 0.f, 0.f, 0.f};

  stage_tile(cq + (size_t)tile0 * TILE_BYTES, Bs[0], w, lane);

  for (int t = 0; t < CTILES; t++) {
    __syncthreads();   // implicit vmcnt(0): stage(t) landed (issued a full tile ago)
    if (t + 1 < CTILES)
      stage_tile(cq + (size_t)(tile0 + t + 1) * TILE_BYTES, Bs[(t + 1) & 1], w, lane);

    const char* buf = Bs[t & 1];
    #pragma unroll
    for (int cf = 0; cf < 4; cf++) {
      const int col = cf * 16 + fr;
      i32x8 bf[2];
      #pragma unroll
      for (int kh = 0; kh < 2; kh++) {
        const int kb = kh * 4 + kq;
        const int off = kb * 2048 + col * 16;
        i32x4 lo = *(const i32x4*)(buf + off);
        i32x4 hi = *(const i32x4*)(buf + off + 1024);
        i32x8 b;
        #pragma unroll
        for (int q = 0; q < 4; q++) { b[q] = lo[q]; b[q + 4] = hi[q]; }
        bf[kh] = b;
      }
      f32x4 acc[2];
      #pragma unroll
      for (int rf = 0; rf < 2; rf++) {
        acc[rf] = __builtin_amdgcn_mfma_scale_f32_16x16x128_f8f6f4(
            a[rf][0], bf[0], vzero, 0, 0, 0, 0x7F7F7F7F, 0, 0x7F7F7F7F);
        acc[rf] = __builtin_amdgcn_mfma_scale_f32_16x16x128_f8f6f4(
            a[rf][1], bf[1], acc[rf], 0, 0, 0, 0x7F7F7F7F, 0, 0x7F7F7F7F);
      }
      // exp + accumulate (A pre-scaled: acc is already the exp2 argument)
      #pragma unroll
      for (int rf = 0; rf < 2; rf++)
        #pragma unroll
        for (int r = 0; r < 4; r++)
          s[rf][r] += __builtin_amdgcn_exp2f(acc[rf][r]);
    }
  }

  // reduce across the 16 col-lanes of each row-group, then write partials
  #pragma unroll
  for (int rf = 0; rf < 2; rf++)
    #pragma unroll
    for (int r = 0; r < 4; r++) {
      float v = s[rf][r];
      v += __shfl_xor(v, 1, 64);
      v += __shfl_xor(v, 2, 64);
      v += __shfl_xor(v, 4, 64);
      v += __shfl_xor(v, 8, 64);
      s[rf][r] = v;
    }
  if (fr == 0) {
    int rowbase = brow0 + w * 32;
    #pragma unroll
    for (int rf = 0; rf < 2; rf++)
      #pragma unroll
      for (int r = 0; r < 4; r++)
        partials[(size_t)cs * B_ROWS + rowbase + rf * 16 + kq * 4 + r] = s[rf][r];
  }
}

// ---- kernel 3: combine ----
__global__ void finalize(const float* __restrict__ partials, const float* __restrict__ elab,
                         float* __restrict__ out) {
  int b = blockIdx.x * blockDim.x + threadIdx.x;
  if (b >= B_ROWS) return;
  float ssum = 0.f;
  #pragma unroll
  for (int cs = 0; cs < CSPLIT; cs++) ssum += partials[(size_t)cs * B_ROWS + b];
  out[b] = elab[b] / ssum;
}

extern "C" void kernel_launch(void* const* d_in, const int* in_sizes, int n_in,
                              void* d_out, int out_size, void* d_ws, size_t ws_size,
                              hipStream_t stream) {
  const float* x = (const float*)d_in[0];
  const float* cent = (const float*)d_in[1];
  const int* labels = (const int*)d_in[2];
  float* out = (float*)d_out;

  char* ws = (char*)d_ws;
  uint8_t* xq = (uint8_t*)ws;                               // 4096*256  = 1 MB
  uint8_t* cq = (uint8_t*)(ws + (size_t)B_ROWS * D_DIM);    // 32768*256 = 8 MB
  float* partials = (float*)(ws + (size_t)B_ROWS * D_DIM + (size_t)C_COLS * D_DIM);
  float* elab = partials + (size_t)CSPLIT * B_ROWS;         // + 1 MB, elab 16 KB

  prep_all<<<CVT_TILES + B_ROWS / 4, 256, 0, stream>>>(x, cent, labels, cq, xq, elab);
  gemm_expsum<<<dim3(B_ROWS / BM * CSPLIT), 512, 0, stream>>>(xq, cq, partials);
  finalize<<<B_ROWS / 256, 256, 0, stream>>>(partials, elab, out);
}

// Round 13
// 71.874 us; speedup vs baseline: 1.2611x; 1.2611x over previous
//
#include <hip/hip_runtime.h>
#include <stdint.h>

typedef int i32x4 __attribute__((ext_vector_type(4)));
typedef int i32x8 __attribute__((ext_vector_type(8)));
typedef float f32x4 __attribute__((ext_vector_type(4)));

#define B_ROWS 4096
#define C_COLS 32768
#define D_DIM 256
// log2(e) / 0.05
#define LOG2E_OVER_TEMP 28.853900817779268f

#define BM 256                   // rows per block (4 waves x 64 rows)
#define BC 32                    // cols per wave-private LDS tile (8 KB)
#define CSPLIT 64
#define CPB (C_COLS / CSPLIT)    // 512 cols per block
#define NTILES (CPB / BC)        // 16 tiles
#define NWAVES 4
#define TILE_BYTES (BC * D_DIM)  // 8192 (fp8)
#define CVT_TILES (C_COLS / BC)  // 1024

typedef __attribute__((address_space(3))) char lds_char_t;
typedef __attribute__((address_space(1))) const char glb_char_t;

// pack 4 f32 -> 4 fp8 e4m3 bytes in one dword (saturating HW cvt)
__device__ __forceinline__ int pack4_fp8(float a, float b, float c, float d) {
  int r = 0;
  r = __builtin_amdgcn_cvt_pk_fp8_f32(a, b, r, false);  // bytes 0,1
  r = __builtin_amdgcn_cvt_pk_fp8_f32(c, d, r, true);   // bytes 2,3
  return r;
}

// ---- kernel 1: prep ----
// blocks [0, 1024): centrals f32 -> fp8 e4m3, permuted per 32-col tile:
//   cq[tile][kb(8)][half(2)][col(32)][16B], 8 KB/tile. Reads fully coalesced
//   (lane i reads 64B at tsrc + 64*i); 16B permuted writes merge into 64B
//   wave segments.
// blocks [1024, ...): row-normalize x (pre-scaled by log2e/T) -> fp8 xq,
//   plus exact fp32 label logit -> elab. One wave per row.
__global__ void prep_all(const float* __restrict__ x, const float* __restrict__ cent,
                         const int* __restrict__ labels, uint8_t* __restrict__ cq,
                         uint8_t* __restrict__ xq, float* __restrict__ elab) {
  int blk = blockIdx.x;
  if (blk < CVT_TILES) {
    int ct = blk;
    const float* tsrc = cent + (size_t)ct * BC * D_DIM;
    uint8_t* tdst = cq + (size_t)ct * TILE_BYTES;
    #pragma unroll
    for (int i = 0; i < 2; i++) {
      int c = i * 256 + threadIdx.x;      // chunk 0..511: 16 consecutive floats
      int col = c >> 4;                   // 0..31 (central row within tile)
      int k16 = c & 15;                   // 16-float k group
      const float* src = tsrc + c * 16;   // coalesced
      int4 o;
      float4 v;
      v = ((const float4*)src)[0]; o.x = pack4_fp8(v.x, v.y, v.z, v.w);
      v = ((const float4*)src)[1]; o.y = pack4_fp8(v.x, v.y, v.z, v.w);
      v = ((const float4*)src)[2]; o.z = pack4_fp8(v.x, v.y, v.z, v.w);
      v = ((const float4*)src)[3]; o.w = pack4_fp8(v.x, v.y, v.z, v.w);
      // permuted slot: kb = k16>>1, half = k16&1
      int off = (k16 >> 1) * 1024 + (k16 & 1) * 512 + col * 16;
      *(int4*)(tdst + off) = o;
    }
  } else {
    int row = (blk - CVT_TILES) * (blockDim.x >> 6) + (threadIdx.x >> 6);
    int lane = threadIdx.x & 63;
    int lab = labels[row];
    const float4 xv = *(const float4*)(x + (size_t)row * D_DIM + lane * 4);
    const float4 cv = *(const float4*)(cent + (size_t)lab * D_DIM + lane * 4);
    float ss = xv.x * xv.x + xv.y * xv.y + xv.z * xv.z + xv.w * xv.w;
    float dc = xv.x * cv.x + xv.y * cv.y + xv.z * cv.z + xv.w * cv.w;
    #pragma unroll
    for (int m = 1; m < 64; m <<= 1) {
      ss += __shfl_xor(ss, m, 64);
      dc += __shfl_xor(dc, m, 64);
    }
    float inv = 1.0f / sqrtf(ss);
    float sc = inv * LOG2E_OVER_TEMP;   // pre-scale: GEMM acc is the exp2 arg
    *(int*)(xq + (size_t)row * D_DIM + lane * 4) =
        pack4_fp8(xv.x * sc, xv.y * sc, xv.z * sc, xv.w * sc);
    if (lane == 0) elab[row] = exp2f(dc * inv * LOG2E_OVER_TEMP);
  }
}

// ---- per-WAVE staging: async global->LDS into this wave's private buffer ----
// 8 x global_load_lds x 16B/lane = 8 KB tile. Increments vmcnt by 8.
__device__ __forceinline__ void stage_tile_wave(const uint8_t* __restrict__ src,
                                                char* buf, int lane) {
  #pragma unroll
  for (int i = 0; i < 8; i++) {
    __builtin_amdgcn_global_load_lds(
        (glb_char_t*)(const void*)(src + i * 1024 + lane * 16),
        (lds_char_t*)(void*)(buf + i * 1024), 16, 0, 0);
  }
}

// ---- kernel 2: fused MX-fp8 GEMM + exp + row-sum ----
// BARRIER-FREE wave-private pipeline (rounds 2-12 lesson: reg demand ~130 pins
// this body at 2 waves/SIMD, so __syncthreads lockstep can't be hidden by TLP;
// and launch_bounds >2 waves/EU splits the unified RF and spills. Instead each
// wave owns a private 2x8KB LDS double-buffer and syncs ONLY its own loads via
// counted vmcnt -- stage(t+1) stays in flight while tile t is consumed, and
// SIMD-coresident waves drift phases so MFMA and exp/VALU overlap).
//   stage(t+1) -> s_waitcnt vmcnt(8) -> consume(t)      [last tile: vmcnt(0)]
// The 4 waves stage identical bytes (4x issue, L1-broadcast so ~1x L2 traffic).
// B tile layout (pre-permuted cq): chunk (col, kb, half) at kb*1024 + half*512
// + col*16. B-frag = two i32x4 LDS reads (never one i32x8 deref -- spill guard).
// MFMA: mfma_scale_f32_16x16x128_f8f6f4, unit scales (e8m0 0x7F = 2^0).
__global__ void __launch_bounds__(256, 2)
gemm_expsum(const uint8_t* __restrict__ xq, const uint8_t* __restrict__ cq,
            float* __restrict__ partials) {
  __shared__ char Bs[NWAVES][2][TILE_BYTES];   // 4 x 2 x 8 KB = 64 KB
  const int tid = threadIdx.x;
  const int w = tid >> 6, lane = tid & 63;
  const int fr = lane & 15, kq = lane >> 4;

  // XCD-aware decode: xcd = bid&7 owns cs in [xcd*8, xcd*8+8); within an xcd,
  // consecutive j sweep row-blocks of the SAME cs -> B slice stays L2-hot.
  const int bid = blockIdx.x;
  const int xcd = bid & 7;
  const int j = bid >> 3;                  // 0..127
  const int bx = j & 15;                   // row-block 0..15
  const int cs = xcd * 8 + (j >> 4);       // col-split 0..63
  const int brow0 = bx * BM;
  const int tile0 = cs * NTILES;           // global 32-col tile index

  // A fragments: rows brow0 + w*64 + rf*16 + fr; k = kh*128 + kq*32 .. +32
  i32x8 a[4][2];
  #pragma unroll
  for (int rf = 0; rf < 4; rf++) {
    int row = brow0 + w * 64 + rf * 16 + fr;
    #pragma unroll
    for (int kh = 0; kh < 2; kh++)
      a[rf][kh] = *(const i32x8*)(xq + (size_t)row * D_DIM + kh * 128 + kq * 32);
  }

  float s[4][4] = {{0.f,0.f,0.f,0.f},{0.f,0.f,0.f,0.f},{0.f,0.f,0.f,0.f},{0.f,0.f,0.f,0.f}};
  const f32x4 vzero = {0.f, 0.f, 0.f, 0.f};

  const uint8_t* csrc = cq + (size_t)tile0 * TILE_BYTES;
  stage_tile_wave(csrc, Bs[w][0], lane);

  for (int t = 0; t < NTILES; t++) {
    if (t + 1 < NTILES) {
      stage_tile_wave(csrc + (size_t)(t + 1) * TILE_BYTES, Bs[w][(t + 1) & 1], lane);
      asm volatile("s_waitcnt vmcnt(8)" ::: "memory");   // stage(t) landed; t+1 in flight
    } else {
      asm volatile("s_waitcnt vmcnt(0)" ::: "memory");   // drain last stage
    }
    __builtin_amdgcn_sched_barrier(0);                   // keep ds_reads below the wait

    const char* buf = Bs[w][t & 1];
    #pragma unroll
    for (int cf = 0; cf < 2; cf++) {
      const int col = cf * 16 + fr;
      i32x8 bf[2];
      #pragma unroll
      for (int kh = 0; kh < 2; kh++) {
        const int kb = kh * 4 + kq;
        const int off = kb * 1024 + col * 16;
        i32x4 lo = *(const i32x4*)(buf + off);
        i32x4 hi = *(const i32x4*)(buf + off + 512);
        i32x8 b;
        #pragma unroll
        for (int q = 0; q < 4; q++) { b[q] = lo[q]; b[q + 4] = hi[q]; }
        bf[kh] = b;
      }
      f32x4 acc[4];
      #pragma unroll
      for (int rf = 0; rf < 4; rf++) {
        acc[rf] = __builtin_amdgcn_mfma_scale_f32_16x16x128_f8f6f4(
            a[rf][0], bf[0], vzero, 0, 0, 0, 0x7F7F7F7F, 0, 0x7F7F7F7F);
        acc[rf] = __builtin_amdgcn_mfma_scale_f32_16x16x128_f8f6f4(
            a[rf][1], bf[1], acc[rf], 0, 0, 0, 0x7F7F7F7F, 0, 0x7F7F7F7F);
      }
      // exp + accumulate (A pre-scaled: acc is already the exp2 argument)
      #pragma unroll
      for (int rf = 0; rf < 4; rf++)
        #pragma unroll
        for (int r = 0; r < 4; r++)
          s[rf][r] += __builtin_amdgcn_exp2f(acc[rf][r]);
    }
  }

  // reduce across the 16 col-lanes of each row-group, then write partials
  #pragma unroll
  for (int rf = 0; rf < 4; rf++)
    #pragma unroll
    for (int r = 0; r < 4; r++) {
      float v = s[rf][r];
      v += __shfl_xor(v, 1, 64);
      v += __shfl_xor(v, 2, 64);
      v += __shfl_xor(v, 4, 64);
      v += __shfl_xor(v, 8, 64);
      s[rf][r] = v;
    }
  if (fr == 0) {
    int rowbase = brow0 + w * 64;
    #pragma unroll
    for (int rf = 0; rf < 4; rf++)
      #pragma unroll
      for (int r = 0; r < 4; r++)
        partials[(size_t)cs * B_ROWS + rowbase + rf * 16 + kq * 4 + r] = s[rf][r];
  }
}

// ---- kernel 3: combine ----
__global__ void finalize(const float* __restrict__ partials, const float* __restrict__ elab,
                         float* __restrict__ out) {
  int b = blockIdx.x * blockDim.x + threadIdx.x;
  if (b >= B_ROWS) return;
  float ssum = 0.f;
  #pragma unroll
  for (int cs = 0; cs < CSPLIT; cs++) ssum += partials[(size_t)cs * B_ROWS + b];
  out[b] = elab[b] / ssum;
}

extern "C" void kernel_launch(void* const* d_in, const int* in_sizes, int n_in,
                              void* d_out, int out_size, void* d_ws, size_t ws_size,
                              hipStream_t stream) {
  const float* x = (const float*)d_in[0];
  const float* cent = (const float*)d_in[1];
  const int* labels = (const int*)d_in[2];
  float* out = (float*)d_out;

  char* ws = (char*)d_ws;
  uint8_t* xq = (uint8_t*)ws;                               // 4096*256  = 1 MB
  uint8_t* cq = (uint8_t*)(ws + (size_t)B_ROWS * D_DIM);    // 32768*256 = 8 MB
  float* partials = (float*)(ws + (size_t)B_ROWS * D_DIM + (size_t)C_COLS * D_DIM);
  float* elab = partials + (size_t)CSPLIT * B_ROWS;         // + 1 MB, elab 16 KB

  prep_all<<<CVT_TILES + B_ROWS / 4, 256, 0, stream>>>(x, cent, labels, cq, xq, elab);
  gemm_expsum<<<dim3(B_ROWS / BM * CSPLIT), 256, 0, stream>>>(xq, cq, partials);
  finalize<<<B_ROWS / 256, 256, 0, stream>>>(partials, elab, out);
}